// Round 4
// baseline (366.122 us; speedup 1.0000x reference)
//
#include <hip/hip_runtime.h>

#define D 360
#define NAG 64
#define NB 120
#define NPAN 3
#define NQ 30                       // float4 per panel-row slab (120 cols)
#define COV_OFF (NAG * D)
#define INIT_OFF (COV_OFF + NAG * D * D)
// R stash in d_ws: [parity][agent][slot 0..3][120 rows][60 cols]
#define SB(par, ag, slot) ((((size_t)(par) * NAG + (ag)) * 4 + (slot)) * 7200)

__device__ __forceinline__ int gshift(int i) {
    return ((i % 60) < 58) ? (i + 2) : i;
}

// ------- build: S (upd) / final cov (others) + mean/flag + R0 stash ---------
__global__ __launch_bounds__(384) void build_kernel(
    const float* __restrict__ P, const float* __restrict__ mean_in,
    const float* __restrict__ obs, const float* __restrict__ rs,
    const int* __restrict__ init_f, const int* __restrict__ sel_f,
    float* __restrict__ out, float* __restrict__ rb)
{
    const int by = blockIdx.x, ag = blockIdx.y, t = threadIdx.x;
    const bool ini = init_f[ag] != 0, sel = sel_f[ag] != 0;
    const float c = rs[ag] + 1.0f;
    if (by == 45) {   // fused "small" block: mean passthrough/init + flag
        if (t < D) {
            float v = (sel && !ini) ? obs[ag * D + t] : mean_in[ag * D + t];
            out[ag * D + t] = v;     // upd agents overwritten by solve_mean
        }
        if (t == 0) out[INIT_OFF + ag] = (ini || sel) ? 1.0f : 0.0f;
        return;
    }
    if (t >= D) return;
    const float* Pa = P + (size_t)ag * D * D;
    float* cov = out + COV_OFF + (size_t)ag * D * D;
    const int j = t;
    if (sel && ini) {
        const int gj = gshift(j);
        #pragma unroll
        for (int s = 0; s < 8; ++s) {
            const int i = by * 8 + s;
            float v = Pa[(size_t)gshift(i) * D + gj];
            if (i == j) v += 1.0f + c;           // + process(1) + obs(c)
            cov[(size_t)i * D + j] = v;
            if (i < NB && j >= NB)               // stash R slices for pass 0
                rb[SB(0, ag, j / 60 - 2) + i * 60 + (j % 60)] = v;
        }
    } else if (sel) {
        #pragma unroll
        for (int s = 0; s < 8; ++s) {
            const int i = by * 8 + s;
            cov[(size_t)i * D + j] = Pa[(size_t)i * D + j] + ((i == j) ? c : 0.0f);
        }
    } else {
        #pragma unroll
        for (int s = 0; s < 8; ++s) {
            const int i = by * 8 + s;
            cov[(size_t)i * D + j] = Pa[(size_t)i * D + j];
        }
    }
}

// ---------------- 4x4 in-place GJ inverse (no pivoting; SPD blocks) ----------
__device__ __forceinline__ void inv4(float4& m0, float4& m1, float4& m2, float4& m3)
{
    float pv, f;
    pv = 1.0f / m0.x;
    m0.y *= pv; m0.z *= pv; m0.w *= pv; m0.x = pv;
    f = m1.x; m1.y = fmaf(-f, m0.y, m1.y); m1.z = fmaf(-f, m0.z, m1.z); m1.w = fmaf(-f, m0.w, m1.w); m1.x = -f * pv;
    f = m2.x; m2.y = fmaf(-f, m0.y, m2.y); m2.z = fmaf(-f, m0.z, m2.z); m2.w = fmaf(-f, m0.w, m2.w); m2.x = -f * pv;
    f = m3.x; m3.y = fmaf(-f, m0.y, m3.y); m3.z = fmaf(-f, m0.z, m3.z); m3.w = fmaf(-f, m0.w, m3.w); m3.x = -f * pv;
    pv = 1.0f / m1.y;
    m1.x *= pv; m1.z *= pv; m1.w *= pv; m1.y = pv;
    f = m0.y; m0.x = fmaf(-f, m1.x, m0.x); m0.z = fmaf(-f, m1.z, m0.z); m0.w = fmaf(-f, m1.w, m0.w); m0.y = -f * pv;
    f = m2.y; m2.x = fmaf(-f, m1.x, m2.x); m2.z = fmaf(-f, m1.z, m2.z); m2.w = fmaf(-f, m1.w, m2.w); m2.y = -f * pv;
    f = m3.y; m3.x = fmaf(-f, m1.x, m3.x); m3.z = fmaf(-f, m1.z, m3.z); m3.w = fmaf(-f, m1.w, m3.w); m3.y = -f * pv;
    pv = 1.0f / m2.z;
    m2.x *= pv; m2.y *= pv; m2.w *= pv; m2.z = pv;
    f = m0.z; m0.x = fmaf(-f, m2.x, m0.x); m0.y = fmaf(-f, m2.y, m0.y); m0.w = fmaf(-f, m2.w, m0.w); m0.z = -f * pv;
    f = m1.z; m1.x = fmaf(-f, m2.x, m1.x); m1.y = fmaf(-f, m2.y, m1.y); m1.w = fmaf(-f, m2.w, m1.w); m1.z = -f * pv;
    f = m3.z; m3.x = fmaf(-f, m2.x, m3.x); m3.y = fmaf(-f, m2.y, m3.y); m3.w = fmaf(-f, m2.w, m3.w); m3.z = -f * pv;
    pv = 1.0f / m3.w;
    m3.x *= pv; m3.y *= pv; m3.z *= pv; m3.w = pv;
    f = m0.w; m0.x = fmaf(-f, m3.x, m0.x); m0.y = fmaf(-f, m3.y, m0.y); m0.z = fmaf(-f, m3.z, m0.z); m0.w = -f * pv;
    f = m1.w; m1.x = fmaf(-f, m3.x, m1.x); m1.y = fmaf(-f, m3.y, m1.y); m1.z = fmaf(-f, m3.z, m1.z); m1.w = -f * pv;
    f = m2.w; m2.x = fmaf(-f, m3.x, m2.x); m2.y = fmaf(-f, m3.y, m2.y); m2.z = fmaf(-f, m3.z, m2.z); m2.w = -f * pv;
}

// ---------------- factor: block-pivot (mb=4) GJ on the 360x120 panel slab ----
template<int KB>
__device__ __forceinline__ void gj_step(float4 (&row)[NQ], int r, int rel,
                                        float4 (&praw)[2][4][NQ])
{
    const int buf = KB & 1;
    float4 m0 = praw[buf][0][KB];
    float4 m1 = praw[buf][1][KB];
    float4 m2 = praw[buf][2][KB];
    float4 m3 = praw[buf][3][KB];
    inv4(m0, m1, m2, m3);
    if (r < D) {
        const bool is_piv = (rel >= 4 * KB) && (rel < 4 * KB + 4);
        float4 sc;
        if (is_piv) {
            const int i = rel - 4 * KB;
            sc = (i == 0) ? m0 : (i == 1) ? m1 : (i == 2) ? m2 : m3;
            #pragma unroll
            for (int q = 0; q < NQ; ++q)
                if (q != KB) row[q] = make_float4(0.f, 0.f, 0.f, 0.f);
        } else {
            float4 fr = row[KB];
            sc.x = -(fr.x * m0.x + fr.y * m1.x + fr.z * m2.x + fr.w * m3.x);
            sc.y = -(fr.x * m0.y + fr.y * m1.y + fr.z * m2.y + fr.w * m3.y);
            sc.z = -(fr.x * m0.z + fr.y * m1.z + fr.z * m2.z + fr.w * m3.z);
            sc.w = -(fr.x * m0.w + fr.y * m1.w + fr.z * m2.w + fr.w * m3.w);
        }
        #pragma unroll
        for (int q = 0; q < NQ; ++q) {
            if (q == KB) continue;
            float4 p0 = praw[buf][0][q];
            float4 p1 = praw[buf][1][q];
            float4 p2 = praw[buf][2][q];
            float4 p3 = praw[buf][3][q];
            row[q].x = fmaf(sc.x, p0.x, fmaf(sc.y, p1.x, fmaf(sc.z, p2.x, fmaf(sc.w, p3.x, row[q].x))));
            row[q].y = fmaf(sc.x, p0.y, fmaf(sc.y, p1.y, fmaf(sc.z, p2.y, fmaf(sc.w, p3.y, row[q].y))));
            row[q].z = fmaf(sc.x, p0.z, fmaf(sc.y, p1.z, fmaf(sc.z, p2.z, fmaf(sc.w, p3.z, row[q].z))));
            row[q].w = fmaf(sc.x, p0.w, fmaf(sc.y, p1.w, fmaf(sc.z, p2.w, fmaf(sc.w, p3.w, row[q].w))));
        }
        row[KB] = sc;
        if (KB < NQ - 1 && rel >= 4 * (KB + 1) && rel < 4 * (KB + 1) + 4) {
            const int i = rel - 4 * (KB + 1);
            #pragma unroll
            for (int q = 0; q < NQ; ++q) praw[buf ^ 1][i][q] = row[q];
        }
    }
    __syncthreads();
}

template<int KB> struct GJSteps {
    __device__ static __forceinline__ void run(float4 (&row)[NQ], int r, int rel,
                                               float4 (&praw)[2][4][NQ]) {
        gj_step<KB>(row, r, rel, praw);
        GJSteps<KB + 1>::run(row, r, rel, praw);
    }
};
template<> struct GJSteps<NQ> {
    __device__ static __forceinline__ void run(float4 (&)[NQ], int, int, float4 (&)[2][4][NQ]) {}
};

__global__ __launch_bounds__(384) void factor_kernel(
    float* __restrict__ out, const float* __restrict__ rs,
    const int* __restrict__ init_f, const int* __restrict__ sel_f,
    float* __restrict__ rb, int p)
{
    const int ag = blockIdx.x;
    if (!(init_f[ag] && sel_f[ag])) return;
    float* M = out + COV_OFF + (size_t)ag * D * D;
    const int j0 = p * NB;
    const int r = threadIdx.x;
    const int rel = r - j0;
    float4 row[NQ];
    if (r < D) {
        const float* src = M + (size_t)r * D + j0;
        #pragma unroll
        for (int q = 0; q < NQ; ++q) row[q] = *(const float4*)(src + 4 * q);
    }
    __shared__ float4 praw[2][4][NQ];
    if (rel >= 0 && rel < 4) {
        #pragma unroll
        for (int q = 0; q < NQ; ++q) praw[0][rel][q] = row[q];
    }
    __syncthreads();
    GJSteps<0>::run(row, r, rel, praw);
    if (r < D) {
        float* dst = M + (size_t)r * D + j0;
        if (p == NPAN - 1) {
            // last panel: fold finalize  cov = c*I - c^2 * Sinv  on panel cols
            const float c = rs[ag] + 1.0f;
            const float c2 = c * c;
            #pragma unroll
            for (int q = 0; q < NQ; ++q) {
                const int cg = j0 + 4 * q;
                float4 o;
                o.x = ((r == cg + 0) ? c : 0.f) - c2 * row[q].x;
                o.y = ((r == cg + 1) ? c : 0.f) - c2 * row[q].y;
                o.z = ((r == cg + 2) ? c : 0.f) - c2 * row[q].z;
                o.w = ((r == cg + 3) ? c : 0.f) - c2 * row[q].w;
                *(float4*)(dst + 4 * q) = o;
            }
        } else {
            #pragma unroll
            for (int q = 0; q < NQ; ++q) *(float4*)(dst + 4 * q) = row[q];
            // stash next pass's R slices (rows of next panel, these panel cols)
            const int nrel = r - NB * (p + 1);
            if (nrel >= 0 && nrel < NB) {
                #pragma unroll
                for (int q = 0; q < NQ; ++q) {
                    const int slot = 2 * p + (q >= 15);
                    float* rdst = rb + SB((p + 1) & 1, ag, slot) + nrel * 60 + (q % 15) * 4;
                    *(float4*)rdst = row[q];
                }
            }
        }
    }
}

// -------- update: M[rt,ct] = (panelrow?0:M) + F*R ; K=120 -------------------
__device__ __forceinline__ void mm_row(const float4 a, const float4 b0, const float4 b1,
                                       const float4 b2, const float4 b3, float acc[4]) {
    acc[0] = fmaf(a.x, b0.x, fmaf(a.y, b1.x, fmaf(a.z, b2.x, fmaf(a.w, b3.x, acc[0]))));
    acc[1] = fmaf(a.x, b0.y, fmaf(a.y, b1.y, fmaf(a.z, b2.y, fmaf(a.w, b3.y, acc[1]))));
    acc[2] = fmaf(a.x, b0.z, fmaf(a.y, b1.z, fmaf(a.z, b2.z, fmaf(a.w, b3.z, acc[2]))));
    acc[3] = fmaf(a.x, b0.w, fmaf(a.y, b1.w, fmaf(a.z, b2.w, fmaf(a.w, b3.w, acc[3]))));
}

__global__ __launch_bounds__(256) void update_kernel(
    float* __restrict__ out, const float* __restrict__ rs,
    const int* __restrict__ init_f, const int* __restrict__ sel_f,
    float* __restrict__ rb, int p)
{
    const int ag = blockIdx.x;
    if (!(init_f[ag] && sel_f[ag])) return;
    const int y = blockIdx.y;                    // 0..3
    const int ct = y + (y >= 2 * p ? 2 : 0);     // global 60-col tile, skip panel
    const int rt = blockIdx.z;                   // 0..5 (60-row tile)
    const int r0 = 60 * rt, c0 = 60 * ct;
    const bool panelrow = ((rt >> 1) == p);
    float* M = out + COV_OFF + (size_t)ag * D * D;
    const float c = rs[ag] + 1.0f;
    const float c2 = c * c;
    __shared__ float R[NB][60];      // [k][j]  K=120
    __shared__ float F[60][NB + 4];  // [r][k]
    const int t = threadIdx.x;
    {   // R from the race-free stash
        const float* rsrc = rb + SB(p & 1, ag, y);
        for (int idx = t; idx < 120 * 15; idx += 256) {
            const int k = idx / 15, q = idx % 15;
            *(float4*)&R[k][4 * q] = *(const float4*)(rsrc + k * 60 + 4 * q);
        }
    }
    {   // F = factored panel, rows r0..r0+59
        for (int idx = t; idx < 60 * NQ; idx += 256) {
            const int row = idx / NQ, q = idx % NQ;
            float4 v = *(const float4*)(M + (size_t)(r0 + row) * D + p * NB + 4 * q);
            if (p == NPAN - 1) {
                // factor already wrote transformed panel: recover raw F
                const int rg = r0 + row, cg = p * NB + 4 * q;
                v.x = (((rg == cg + 0) ? c : 0.f) - v.x) / c2;
                v.y = (((rg == cg + 1) ? c : 0.f) - v.y) / c2;
                v.z = (((rg == cg + 2) ? c : 0.f) - v.z) / c2;
                v.w = (((rg == cg + 3) ? c : 0.f) - v.w) / c2;
            }
            *(float4*)&F[row][4 * q] = v;
        }
    }
    __syncthreads();
    const int tx = t % 16, ty = t / 16;
    if (tx < 15 && ty < 15) {
        float acc[4][4];
        #pragma unroll
        for (int i = 0; i < 4; ++i)
            #pragma unroll
            for (int j = 0; j < 4; ++j) acc[i][j] = 0.0f;
        for (int kq = 0; kq < NQ; ++kq) {
            float4 a0 = *(const float4*)&F[4 * ty + 0][4 * kq];
            float4 a1 = *(const float4*)&F[4 * ty + 1][4 * kq];
            float4 a2 = *(const float4*)&F[4 * ty + 2][4 * kq];
            float4 a3 = *(const float4*)&F[4 * ty + 3][4 * kq];
            float4 b0 = *(const float4*)&R[4 * kq + 0][4 * tx];
            float4 b1 = *(const float4*)&R[4 * kq + 1][4 * tx];
            float4 b2 = *(const float4*)&R[4 * kq + 2][4 * tx];
            float4 b3 = *(const float4*)&R[4 * kq + 3][4 * tx];
            mm_row(a0, b0, b1, b2, b3, acc[0]);
            mm_row(a1, b0, b1, b2, b3, acc[1]);
            mm_row(a2, b0, b1, b2, b3, acc[2]);
            mm_row(a3, b0, b1, b2, b3, acc[3]);
        }
        #pragma unroll
        for (int i = 0; i < 4; ++i) {
            const int rg = r0 + 4 * ty + i;
            float* dst = M + (size_t)rg * D + c0 + 4 * tx;
            float4 base;
            if (panelrow) { base = make_float4(0.f, 0.f, 0.f, 0.f); }
            else          { base = *(const float4*)dst; }
            float4 v;
            v.x = base.x + acc[i][0];
            v.y = base.y + acc[i][1];
            v.z = base.z + acc[i][2];
            v.w = base.w + acc[i][3];
            if (p < NPAN - 1) {
                // stash next pass's R slice (rows of next panel, this col-tile)
                if ((rt >> 1) == p + 1 && (ct >> 1) != p + 1) {
                    const int slot = ct - (ct > 2 * p + 3 ? 2 : 0);
                    const int srow = rg - NB * (p + 1);
                    *(float4*)(rb + SB((p + 1) & 1, ag, slot) + srow * 60 + 4 * tx) = v;
                }
                *(float4*)dst = v;
            } else {
                // last pass: fold finalize  cov = c*I - c^2 * Sinv
                const int cg = c0 + 4 * tx;
                float4 o;
                o.x = ((rg == cg + 0) ? c : 0.f) - c2 * v.x;
                o.y = ((rg == cg + 1) ? c : 0.f) - c2 * v.y;
                o.z = ((rg == cg + 2) ? c : 0.f) - c2 * v.z;
                o.w = ((rg == cg + 3) ? c : 0.f) - c2 * v.w;
                *(float4*)dst = o;
            }
        }
    }
}

// ------- mean: m = obs - c*Sinv*d, via transformed C:  m = obs - d + (C^T d)/c
__global__ __launch_bounds__(384) void solve_mean_kernel(
    float* __restrict__ out, const float* __restrict__ mean_in,
    const float* __restrict__ obs, const float* __restrict__ rs,
    const int* __restrict__ init_f, const int* __restrict__ sel_f)
{
    const int ag = blockIdx.x;
    if (!(init_f[ag] && sel_f[ag])) return;
    const float* C = out + COV_OFF + (size_t)ag * D * D;
    __shared__ float dsh[D];
    const int t = threadIdx.x;
    if (t < D) dsh[t] = obs[ag * D + t] - mean_in[ag * D + gshift(t)];
    __syncthreads();
    if (t < D) {
        float dot = 0.0f;
        #pragma unroll 8
        for (int j = 0; j < D; ++j)
            dot = fmaf(C[(size_t)j * D + t], dsh[j], dot);   // coalesced col read
        const float c = rs[ag] + 1.0f;
        out[ag * D + t] = obs[ag * D + t] - dsh[t] + dot / c;
    }
}

extern "C" void kernel_launch(void* const* d_in, const int* in_sizes, int n_in,
                              void* d_out, int out_size, void* d_ws, size_t ws_size,
                              hipStream_t stream) {
    const float* mean_in     = (const float*)d_in[0];
    const float* P           = (const float*)d_in[1];
    const float* obs         = (const float*)d_in[2];
    const float* rs          = (const float*)d_in[3];
    const int*   initialized = (const int*)d_in[4];
    const int*   selected    = (const int*)d_in[5];
    float* out = (float*)d_out;
    float* rb  = (float*)d_ws;   // 2*64*4*7200 floats = 14.75 MB

    build_kernel<<<dim3(46, NAG), 384, 0, stream>>>(P, mean_in, obs, rs,
                                                    initialized, selected, out, rb);
    for (int p = 0; p < NPAN; ++p) {
        factor_kernel<<<NAG, 384, 0, stream>>>(out, rs, initialized, selected, rb, p);
        update_kernel<<<dim3(NAG, 4, 6), 256, 0, stream>>>(out, rs, initialized,
                                                           selected, rb, p);
    }
    solve_mean_kernel<<<NAG, 384, 0, stream>>>(out, mean_in, obs, rs, initialized, selected);
}

// Round 5
// 303.840 us; speedup vs baseline: 1.2050x; 1.2050x over previous
//
#include <hip/hip_runtime.h>

#define D 360
#define NAG 64
#define NB 60
#define NPAN 6
#define COV_OFF (NAG * D)
#define INIT_OFF (COV_OFF + NAG * D * D)
// ping-pong R stash in d_ws: [parity][agent][ct][60][60]
#define RBOFF(par, ag, ct) ((((par) * NAG + (ag)) * 6 + (ct)) * 3600)

__device__ __forceinline__ int gshift(int i) {
    return ((i % 60) < 58) ? (i + 2) : i;
}

// ------- build: S (upd) / final cov (others) + mean/flag + R0 stash ---------
__global__ __launch_bounds__(384) void build_kernel(
    const float* __restrict__ P, const float* __restrict__ mean_in,
    const float* __restrict__ obs, const float* __restrict__ rs,
    const int* __restrict__ init_f, const int* __restrict__ sel_f,
    float* __restrict__ out, float* __restrict__ rb)
{
    const int by = blockIdx.x, ag = blockIdx.y, t = threadIdx.x;
    const bool ini = init_f[ag] != 0, sel = sel_f[ag] != 0;
    const float c = rs[ag] + 1.0f;
    if (by == 45) {   // fused "small" block: mean passthrough/init + flag
        if (t < D) {
            float v = (sel && !ini) ? obs[ag * D + t] : mean_in[ag * D + t];
            out[ag * D + t] = v;     // upd agents overwritten by solve_mean
        }
        if (t == 0) out[INIT_OFF + ag] = (ini || sel) ? 1.0f : 0.0f;
        return;
    }
    if (t >= D) return;
    const float* Pa = P + (size_t)ag * D * D;
    float* cov = out + COV_OFF + (size_t)ag * D * D;
    const int j = t;
    if (sel && ini) {
        const int gj = gshift(j);
        #pragma unroll
        for (int s = 0; s < 8; ++s) {
            const int i = by * 8 + s;
            float v = Pa[(size_t)gshift(i) * D + gj];
            if (i == j) v += 1.0f + c;           // + process(1) + obs(c)
            cov[(size_t)i * D + j] = v;
            if (i < NB && j >= NB)               // stash R slices for pass 0
                rb[RBOFF(0, ag, j / NB) + i * NB + (j % NB)] = v;
        }
    } else if (sel) {
        #pragma unroll
        for (int s = 0; s < 8; ++s) {
            const int i = by * 8 + s;
            cov[(size_t)i * D + j] = Pa[(size_t)i * D + j] + ((i == j) ? c : 0.0f);
        }
    } else {
        #pragma unroll
        for (int s = 0; s < 8; ++s) {
            const int i = by * 8 + s;
            cov[(size_t)i * D + j] = Pa[(size_t)i * D + j];
        }
    }
}

// ---------------- 4x4 in-place GJ inverse (no pivoting; SPD blocks) ----------
__device__ __forceinline__ void inv4(float4& m0, float4& m1, float4& m2, float4& m3)
{
    float pv, f;
    pv = 1.0f / m0.x;
    m0.y *= pv; m0.z *= pv; m0.w *= pv; m0.x = pv;
    f = m1.x; m1.y = fmaf(-f, m0.y, m1.y); m1.z = fmaf(-f, m0.z, m1.z); m1.w = fmaf(-f, m0.w, m1.w); m1.x = -f * pv;
    f = m2.x; m2.y = fmaf(-f, m0.y, m2.y); m2.z = fmaf(-f, m0.z, m2.z); m2.w = fmaf(-f, m0.w, m2.w); m2.x = -f * pv;
    f = m3.x; m3.y = fmaf(-f, m0.y, m3.y); m3.z = fmaf(-f, m0.z, m3.z); m3.w = fmaf(-f, m0.w, m3.w); m3.x = -f * pv;
    pv = 1.0f / m1.y;
    m1.x *= pv; m1.z *= pv; m1.w *= pv; m1.y = pv;
    f = m0.y; m0.x = fmaf(-f, m1.x, m0.x); m0.z = fmaf(-f, m1.z, m0.z); m0.w = fmaf(-f, m1.w, m0.w); m0.y = -f * pv;
    f = m2.y; m2.x = fmaf(-f, m1.x, m2.x); m2.z = fmaf(-f, m1.z, m2.z); m2.w = fmaf(-f, m1.w, m2.w); m2.y = -f * pv;
    f = m3.y; m3.x = fmaf(-f, m1.x, m3.x); m3.z = fmaf(-f, m1.z, m3.z); m3.w = fmaf(-f, m1.w, m3.w); m3.y = -f * pv;
    pv = 1.0f / m2.z;
    m2.x *= pv; m2.y *= pv; m2.w *= pv; m2.z = pv;
    f = m0.z; m0.x = fmaf(-f, m2.x, m0.x); m0.y = fmaf(-f, m2.y, m0.y); m0.w = fmaf(-f, m2.w, m0.w); m0.z = -f * pv;
    f = m1.z; m1.x = fmaf(-f, m2.x, m1.x); m1.y = fmaf(-f, m2.y, m1.y); m1.w = fmaf(-f, m2.w, m1.w); m1.z = -f * pv;
    f = m3.z; m3.x = fmaf(-f, m2.x, m3.x); m3.y = fmaf(-f, m2.y, m3.y); m3.w = fmaf(-f, m2.w, m3.w); m3.z = -f * pv;
    pv = 1.0f / m3.w;
    m3.x *= pv; m3.y *= pv; m3.z *= pv; m3.w = pv;
    f = m0.w; m0.x = fmaf(-f, m3.x, m0.x); m0.y = fmaf(-f, m3.y, m0.y); m0.z = fmaf(-f, m3.z, m0.z); m0.w = -f * pv;
    f = m1.w; m1.x = fmaf(-f, m3.x, m1.x); m1.y = fmaf(-f, m3.y, m1.y); m1.z = fmaf(-f, m3.z, m1.z); m1.w = -f * pv;
    f = m2.w; m2.x = fmaf(-f, m3.x, m2.x); m2.y = fmaf(-f, m3.y, m2.y); m2.z = fmaf(-f, m3.z, m2.z); m2.w = -f * pv;
}

// ---- named-register slab: 15 float4 members, all access compile-time -------
struct Slab {
    float4 v0, v1, v2, v3, v4, v5, v6, v7, v8, v9, v10, v11, v12, v13, v14;
};
template<int I> __device__ __forceinline__ float4& AT(Slab& s) {
    if constexpr (I == 0) return s.v0;   else if constexpr (I == 1) return s.v1;
    else if constexpr (I == 2) return s.v2;  else if constexpr (I == 3) return s.v3;
    else if constexpr (I == 4) return s.v4;  else if constexpr (I == 5) return s.v5;
    else if constexpr (I == 6) return s.v6;  else if constexpr (I == 7) return s.v7;
    else if constexpr (I == 8) return s.v8;  else if constexpr (I == 9) return s.v9;
    else if constexpr (I == 10) return s.v10; else if constexpr (I == 11) return s.v11;
    else if constexpr (I == 12) return s.v12; else if constexpr (I == 13) return s.v13;
    else return s.v14;
}
template<int Q = 0> __device__ __forceinline__ void slab_load(Slab& s, const float* src) {
    if constexpr (Q < 15) { AT<Q>(s) = *(const float4*)(src + 4 * Q); slab_load<Q + 1>(s, src); }
}
template<int Q = 0> __device__ __forceinline__ void slab_store(Slab& s, float* dst) {
    if constexpr (Q < 15) { *(float4*)(dst + 4 * Q) = AT<Q>(s); slab_store<Q + 1>(s, dst); }
}
template<int Q = 0> __device__ __forceinline__ void slab_stage(Slab& s, float4 (&dst)[15]) {
    if constexpr (Q < 15) { dst[Q] = AT<Q>(s); slab_stage<Q + 1>(s, dst); }
}
template<int KB, int Q = 0> __device__ __forceinline__ void zero_except(Slab& s) {
    if constexpr (Q < 15) {
        if constexpr (Q != KB) AT<Q>(s) = make_float4(0.f, 0.f, 0.f, 0.f);
        zero_except<KB, Q + 1>(s);
    }
}
template<int KB, int Q = 0>
__device__ __forceinline__ void rank4(Slab& s, const float4 sc, const float4 (&pb)[4][15]) {
    if constexpr (Q < 15) {
        if constexpr (Q != KB) {
            const float4 p0 = pb[0][Q], p1 = pb[1][Q], p2 = pb[2][Q], p3 = pb[3][Q];
            float4& r = AT<Q>(s);
            r.x = fmaf(sc.x, p0.x, fmaf(sc.y, p1.x, fmaf(sc.z, p2.x, fmaf(sc.w, p3.x, r.x))));
            r.y = fmaf(sc.x, p0.y, fmaf(sc.y, p1.y, fmaf(sc.z, p2.y, fmaf(sc.w, p3.y, r.y))));
            r.z = fmaf(sc.x, p0.z, fmaf(sc.y, p1.z, fmaf(sc.z, p2.z, fmaf(sc.w, p3.z, r.z))));
            r.w = fmaf(sc.x, p0.w, fmaf(sc.y, p1.w, fmaf(sc.z, p2.w, fmaf(sc.w, p3.w, r.w))));
        }
        rank4<KB, Q + 1>(s, sc, pb);
    }
}
// transformed final store for the last panel: o = (r==cg ? c:0) - c2*v
template<int Q = 0>
__device__ __forceinline__ void slab_store_fin(Slab& s, float* dst, int r, int j0,
                                               float c, float c2) {
    if constexpr (Q < 15) {
        const int cg = j0 + 4 * Q;
        const float4 v = AT<Q>(s);
        float4 o;
        o.x = ((r == cg + 0) ? c : 0.f) - c2 * v.x;
        o.y = ((r == cg + 1) ? c : 0.f) - c2 * v.y;
        o.z = ((r == cg + 2) ? c : 0.f) - c2 * v.z;
        o.w = ((r == cg + 3) ? c : 0.f) - c2 * v.w;
        *(float4*)(dst + 4 * Q) = o;
        slab_store_fin<Q + 1>(s, dst, r, j0, c, c2);
    }
}

// ---------------- factor: block-pivot (mb=4) GJ, slab in named registers ----
template<int KB>
__device__ __forceinline__ void gj_step(Slab& s, int r, int rel, float4 (&praw)[2][4][15])
{
    const int buf = KB & 1;
    float4 m0 = praw[buf][0][KB];
    float4 m1 = praw[buf][1][KB];
    float4 m2 = praw[buf][2][KB];
    float4 m3 = praw[buf][3][KB];
    inv4(m0, m1, m2, m3);
    if (r < D) {
        const bool is_piv = (rel >= 4 * KB) && (rel < 4 * KB + 4);
        float4 sc;
        if (is_piv) {
            const int i = rel - 4 * KB;
            sc = (i == 0) ? m0 : (i == 1) ? m1 : (i == 2) ? m2 : m3;  // Binv row
            zero_except<KB>(s);
        } else {
            const float4 fr = AT<KB>(s);
            sc.x = -(fr.x * m0.x + fr.y * m1.x + fr.z * m2.x + fr.w * m3.x);
            sc.y = -(fr.x * m0.y + fr.y * m1.y + fr.z * m2.y + fr.w * m3.y);
            sc.z = -(fr.x * m0.z + fr.y * m1.z + fr.z * m2.z + fr.w * m3.z);
            sc.w = -(fr.x * m0.w + fr.y * m1.w + fr.z * m2.w + fr.w * m3.w);
        }
        rank4<KB>(s, sc, praw[buf]);
        AT<KB>(s) = sc;
        if (KB < 14 && rel >= 4 * (KB + 1) && rel < 4 * (KB + 1) + 4) {
            slab_stage(s, praw[buf ^ 1][rel - 4 * (KB + 1)]);
        }
    }
    __syncthreads();
}

template<int KB> struct GJ {
    __device__ static __forceinline__ void run(Slab& s, int r, int rel,
                                               float4 (&praw)[2][4][15]) {
        gj_step<KB>(s, r, rel, praw);
        GJ<KB + 1>::run(s, r, rel, praw);
    }
};
template<> struct GJ<15> {
    __device__ static __forceinline__ void run(Slab&, int, int, float4 (&)[2][4][15]) {}
};

__global__ __launch_bounds__(384) void factor_kernel(
    float* __restrict__ out, const float* __restrict__ rs,
    const int* __restrict__ init_f, const int* __restrict__ sel_f,
    float* __restrict__ rb, int p)
{
    const int ag = blockIdx.x;
    if (!(init_f[ag] && sel_f[ag])) return;
    float* M = out + COV_OFF + (size_t)ag * D * D;
    const int j0 = p * NB;
    const int r = threadIdx.x;
    const int rel = r - j0;
    Slab s;
    if (r < D) slab_load(s, M + (size_t)r * D + j0);
    __shared__ float4 praw[2][4][15];
    if (rel >= 0 && rel < 4) slab_stage(s, praw[0][rel]);
    __syncthreads();
    GJ<0>::run(s, r, rel, praw);
    if (r < D) {
        float* dst = M + (size_t)r * D + j0;
        if (p == NPAN - 1) {
            // last panel: fold finalize  cov = c*I - c^2 * Sinv  on panel cols
            const float c = rs[ag] + 1.0f;
            slab_store_fin(s, dst, r, j0, c, c * c);
        } else {
            slab_store(s, dst);
            // stash next pass's R slice for col-tile ct==p (rows of next panel)
            const int nrel = r - NB * (p + 1);
            if (nrel >= 0 && nrel < NB)
                slab_store(s, rb + RBOFF((p + 1) & 1, ag, p) + nrel * NB);
        }
    }
}

// -------- update: M[:,ct] = (rt==p?0:M) + F*R ; R from stash; stash next R ---
__device__ __forceinline__ void mm_row(const float4 a, const float4 b0, const float4 b1,
                                       const float4 b2, const float4 b3, float acc[4]) {
    acc[0] = fmaf(a.x, b0.x, fmaf(a.y, b1.x, fmaf(a.z, b2.x, fmaf(a.w, b3.x, acc[0]))));
    acc[1] = fmaf(a.x, b0.y, fmaf(a.y, b1.y, fmaf(a.z, b2.y, fmaf(a.w, b3.y, acc[1]))));
    acc[2] = fmaf(a.x, b0.z, fmaf(a.y, b1.z, fmaf(a.z, b2.z, fmaf(a.w, b3.z, acc[2]))));
    acc[3] = fmaf(a.x, b0.w, fmaf(a.y, b1.w, fmaf(a.z, b2.w, fmaf(a.w, b3.w, acc[3]))));
}

__global__ __launch_bounds__(256) void update_kernel(
    float* __restrict__ out, const float* __restrict__ rs,
    const int* __restrict__ init_f, const int* __restrict__ sel_f,
    float* __restrict__ rb, int p)
{
    const int ag = blockIdx.x;
    if (!(init_f[ag] && sel_f[ag])) return;
    const int ct = blockIdx.y + (blockIdx.y >= p ? 1 : 0);
    float* M = out + COV_OFF + (size_t)ag * D * D;
    const int j0 = p * NB, c0 = ct * NB;
    const float c = rs[ag] + 1.0f;
    const float c2 = c * c;
    __shared__ float R[NB][NB + 8];
    __shared__ float F[NB][NB + 8];
    const int t = threadIdx.x;
    {   // R from the race-free stash
        const float* rsrc = rb + RBOFF(p & 1, ag, ct);
        for (int idx = t; idx < NB * 15; idx += 256) {
            int k = idx / 15, q = idx % 15;
            *(float4*)&R[k][4 * q] = *(const float4*)(rsrc + k * NB + 4 * q);
        }
    }
    const int tx = t % 16, ty = t / 16;
    for (int rr = 0; rr < 2; ++rr) {
        const int rt = (int)blockIdx.z * 2 + rr;
        const int r0 = rt * NB;
        __syncthreads();
        for (int idx = t; idx < NB * 15; idx += 256) {
            int rrw = idx / 15, q = idx % 15;
            float4 v = *(const float4*)(M + (size_t)(r0 + rrw) * D + j0 + 4 * q);
            if (p == NPAN - 1) {
                // factor wrote transformed panel: recover raw F
                const int rg = r0 + rrw, cg = j0 + 4 * q;
                v.x = (((rg == cg + 0) ? c : 0.f) - v.x) / c2;
                v.y = (((rg == cg + 1) ? c : 0.f) - v.y) / c2;
                v.z = (((rg == cg + 2) ? c : 0.f) - v.z) / c2;
                v.w = (((rg == cg + 3) ? c : 0.f) - v.w) / c2;
            }
            *(float4*)&F[rrw][4 * q] = v;
        }
        __syncthreads();
        if (tx < 15 && ty < 15) {
            float acc[4][4];
            #pragma unroll
            for (int i = 0; i < 4; ++i)
                #pragma unroll
                for (int j = 0; j < 4; ++j) acc[i][j] = 0.0f;
            for (int kq = 0; kq < 15; ++kq) {
                float4 a0 = *(const float4*)&F[4 * ty + 0][4 * kq];
                float4 a1 = *(const float4*)&F[4 * ty + 1][4 * kq];
                float4 a2 = *(const float4*)&F[4 * ty + 2][4 * kq];
                float4 a3 = *(const float4*)&F[4 * ty + 3][4 * kq];
                float4 b0 = *(const float4*)&R[4 * kq + 0][4 * tx];
                float4 b1 = *(const float4*)&R[4 * kq + 1][4 * tx];
                float4 b2 = *(const float4*)&R[4 * kq + 2][4 * tx];
                float4 b3 = *(const float4*)&R[4 * kq + 3][4 * tx];
                mm_row(a0, b0, b1, b2, b3, acc[0]);
                mm_row(a1, b0, b1, b2, b3, acc[1]);
                mm_row(a2, b0, b1, b2, b3, acc[2]);
                mm_row(a3, b0, b1, b2, b3, acc[3]);
            }
            #pragma unroll
            for (int i = 0; i < 4; ++i) {
                const int rg = r0 + 4 * ty + i;
                float* dst = M + (size_t)rg * D + c0 + 4 * tx;
                float4 base;
                if (rt == p) { base = make_float4(0.f, 0.f, 0.f, 0.f); }
                else         { base = *(const float4*)dst; }
                float4 v;
                v.x = base.x + acc[i][0];
                v.y = base.y + acc[i][1];
                v.z = base.z + acc[i][2];
                v.w = base.w + acc[i][3];
                if (p < NPAN - 1) {
                    // stash next pass's R slice (rows of next panel, this col-tile)
                    if (rt == p + 1 && ct != p + 1) {
                        float* rdst = rb + RBOFF((p + 1) & 1, ag, ct) + (4 * ty + i) * NB + 4 * tx;
                        *(float4*)rdst = v;
                    }
                    *(float4*)dst = v;
                } else {
                    // last pass: fold finalize  cov = c*I - c^2 * Sinv
                    const int cg = c0 + 4 * tx;
                    float4 o;
                    o.x = ((rg == cg + 0) ? c : 0.f) - c2 * v.x;
                    o.y = ((rg == cg + 1) ? c : 0.f) - c2 * v.y;
                    o.z = ((rg == cg + 2) ? c : 0.f) - c2 * v.z;
                    o.w = ((rg == cg + 3) ? c : 0.f) - c2 * v.w;
                    *(float4*)dst = o;
                }
            }
        }
    }
}

// ------- mean: m = obs - c*Sinv*d, via transformed C:  m = obs - d + (C^T d)/c
__global__ __launch_bounds__(384) void solve_mean_kernel(
    float* __restrict__ out, const float* __restrict__ mean_in,
    const float* __restrict__ obs, const float* __restrict__ rs,
    const int* __restrict__ init_f, const int* __restrict__ sel_f)
{
    const int ag = blockIdx.x;
    if (!(init_f[ag] && sel_f[ag])) return;
    const float* C = out + COV_OFF + (size_t)ag * D * D;
    __shared__ float dsh[D];
    const int t = threadIdx.x;
    if (t < D) dsh[t] = obs[ag * D + t] - mean_in[ag * D + gshift(t)];
    __syncthreads();
    if (t < D) {
        float dot = 0.0f;
        #pragma unroll 8
        for (int j = 0; j < D; ++j)
            dot = fmaf(C[(size_t)j * D + t], dsh[j], dot);   // coalesced col read
        const float c = rs[ag] + 1.0f;
        out[ag * D + t] = obs[ag * D + t] - dsh[t] + dot / c;
    }
}

extern "C" void kernel_launch(void* const* d_in, const int* in_sizes, int n_in,
                              void* d_out, int out_size, void* d_ws, size_t ws_size,
                              hipStream_t stream) {
    const float* mean_in     = (const float*)d_in[0];
    const float* P           = (const float*)d_in[1];
    const float* obs         = (const float*)d_in[2];
    const float* rs          = (const float*)d_in[3];
    const int*   initialized = (const int*)d_in[4];
    const int*   selected    = (const int*)d_in[5];
    float* out = (float*)d_out;
    float* rb  = (float*)d_ws;   // 2*64*6*3600 floats = 11.1 MB

    build_kernel<<<dim3(46, NAG), 384, 0, stream>>>(P, mean_in, obs, rs,
                                                    initialized, selected, out, rb);
    for (int p = 0; p < NPAN; ++p) {
        factor_kernel<<<NAG, 384, 0, stream>>>(out, rs, initialized, selected, rb, p);
        update_kernel<<<dim3(NAG, NPAN - 1, 3), 256, 0, stream>>>(out, rs, initialized,
                                                                  selected, rb, p);
    }
    solve_mean_kernel<<<NAG, 384, 0, stream>>>(out, mean_in, obs, rs, initialized, selected);
}